// Round 11
// baseline (399.273 us; speedup 1.0000x reference)
//
#include <hip/hip_runtime.h>
#include <math.h>

// DeltaLM: B=4 T=2048 D=512 H=2048 L=3 V=256
// decay einsum == geometric scan S[i]=h[i]+w*S[i-1], w=exp(-softplus(k)).
// Round 27: R26 = 390.8 best. GEMM2 pinned at ~43us across 5 families with
// all pipes idle + FETCH==unique-bytes -> L3-resident, so stage loads see
// ~500-900cy L3 latency; dbuf coverage is only one compute phase (~300-600
// cy). Untried cell: keep BK=64 (big steps) + ONE extra ring slot + counted
// vmcnt -> lead-2 ~ 1200cy > latency. mgemm2 = R10 mgemm<1,128,64,64> body
// verbatim, ring-3 (72KB, still 2 blocks/CU), wvm<6> per step (LPT=6),
// stage ki+2 after barrier (WAR: slot (ki+2)%3=(ki-1)%3 retired). Dedicated
// kernel (rule #19). mgemm1 / prologue / vocab untouched.

constexpr int Bc = 4, Tc = 2048, Dc = 512, Hc = 2048, Vc = 256;
constexpr int TSF = 16, NCF = 128;

typedef __attribute__((ext_vector_type(8))) short short8;
typedef __attribute__((ext_vector_type(4))) float f32x4;

__device__ inline unsigned short f2bf(float f) {  // RNE fp32->bf16
  unsigned int u = __float_as_uint(f);
  u += 0x7fffu + ((u >> 16) & 1u);
  return (unsigned short)(u >> 16);
}

__device__ inline void gload_lds16(const void* g, void* l) {
  __builtin_amdgcn_global_load_lds(
      (const __attribute__((address_space(1))) void*)g,
      (__attribute__((address_space(3))) void*)l, 16, 0, 0);
}

template<int N> __device__ inline void wvm() {
  if constexpr (N == 0)      asm volatile("s_waitcnt vmcnt(0)" ::: "memory");
  else if constexpr (N == 4) asm volatile("s_waitcnt vmcnt(4)" ::: "memory");
  else if constexpr (N == 6) asm volatile("s_waitcnt vmcnt(6)" ::: "memory");
  else if constexpr (N == 8) asm volatile("s_waitcnt vmcnt(8)" ::: "memory");
  else static_assert(N == 0, "unsupported vmcnt");
}
__device__ inline void barrier_raw() {
  asm volatile("s_barrier" ::: "memory");
}

// gelu(z) = 0.5 z (1+erf(z/sqrt2)); erf via A&S 7.1.25, |eps|<=2.5e-5
// (bf16 rel eps ~2e-3 -> approximation error invisible after f2bf)
__device__ inline float gelu_f(float z) {
  float x = z * 0.707106781186547524f;
  float ax = fabsf(x);
  float t = __builtin_amdgcn_rcpf(fmaf(0.47047f, ax, 1.0f));
  float poly = t*(0.3480242f + t*(-0.0958798f + t*0.7478556f));
  float er = 1.0f - poly * __expf(-ax*ax);
  er = copysignf(er, x);
  return 0.5f * z * (1.0f + er);
}

__device__ inline float decay_w(const float* kvec, int l) {
  float kk = kvec[l];
  float sp = kk > 0.f ? kk + log1pf(expf(-kk)) : log1pf(expf(kk));
  return expf(-sp);
}

// ---------- merged weight prep: W1t, W2t (transpose->bf16) + emb ----------
__device__ inline void tr32(const float* Wl, unsigned short* Wtl,
                            int R, int C, int c0, int r0, int tid,
                            float (*tile)[33]) {
  int tx = tid & 31, ty = tid >> 5;
  for (int i = ty; i < 32; i += 8)
    tile[i][tx] = Wl[(size_t)(r0+i)*C + (c0+tx)];
  __syncthreads();
  int rx = tid & 7, ry = tid >> 3;   // ry: c-row 0..31, rx*4: r offset
  ushort4 o;
  o.x = f2bf(tile[rx*4+0][ry]);
  o.y = f2bf(tile[rx*4+1][ry]);
  o.z = f2bf(tile[rx*4+2][ry]);
  o.w = f2bf(tile[rx*4+3][ry]);
  *(ushort4*)&Wtl[(size_t)(c0+ry)*R + (r0 + rx*4)] = o;
}

__global__ __launch_bounds__(256) void wprep(
    const float* __restrict__ W1, unsigned short* __restrict__ W1t,
    const float* __restrict__ W2, unsigned short* __restrict__ W2t,
    const float* __restrict__ embed, unsigned short* __restrict__ emb)
{
  __shared__ float tile[32][33];
  int bid = blockIdx.x, tid = threadIdx.x;
  if (bid < 3072) {            // W1: (L, Dc, Hc) -> (L, Hc, Dc) bf16
    int l = bid >> 10, rem = bid & 1023;
    int cx = rem & 63, ry = rem >> 6;      // C/32=64, R/32=16
    tr32(W1 + (size_t)l*Dc*Hc, W1t + (size_t)l*Dc*Hc, Dc, Hc,
         cx*32, ry*32, tid, tile);
  } else if (bid < 6144) {     // W2: (L, Hc, Dc) -> (L, Dc, Hc) bf16
    int b2 = bid - 3072;
    int l = b2 >> 10, rem = b2 & 1023;
    int cx = rem & 15, ry = rem >> 4;      // C/32=16, R/32=64
    tr32(W2 + (size_t)l*Hc*Dc, W2t + (size_t)l*Hc*Dc, Hc, Dc,
         cx*32, ry*32, tid, tile);
  } else {                     // emb: fp32 -> bf16, 4 elems/thread
    int i = ((bid - 6144)*256 + tid) * 4;
    if (i < Vc*Dc) {
      float4 v = *(const float4*)&embed[i];
      ushort4 o;
      o.x = f2bf(v.x); o.y = f2bf(v.y); o.z = f2bf(v.z); o.w = f2bf(v.w);
      *(ushort4*)&emb[i] = o;
    }
  }
}

// ---------- embed gather + cumprod + tanh + chunk sums (fused) ----------
__global__ __launch_bounds__(1024) void embed_part(
    const int* __restrict__ x, const float* __restrict__ embed,
    float* __restrict__ th, float* __restrict__ partA)
{
  int c = blockIdx.x, b = blockIdx.y;
  int wv = threadIdx.x >> 6, lane = threadIdx.x & 63;
  int token = b*Tc + c*TSF + wv;
  int row = x[token];
  const float* e = embed + (size_t)row * Dc + lane * 8;
  float v[8];
  {
    float4 a = *(const float4*)e;
    float4 bb = *(const float4*)(e + 4);
    v[0]=a.x; v[1]=a.y; v[2]=a.z; v[3]=a.w;
    v[4]=bb.x; v[5]=bb.y; v[6]=bb.z; v[7]=bb.w;
  }
  float p = v[0];
  #pragma unroll
  for (int j=1;j<8;++j) p *= v[j];
  float incl = p;
  #pragma unroll
  for (int off=1; off<64; off<<=1) {
    float t = __shfl_up(incl, off);
    if (lane >= off) incl *= t;
  }
  float excl = __shfl_up(incl, 1);
  if (lane == 0) excl = 1.0f;
  float cc = excl;
  float o[8];
  #pragma unroll
  for (int j=0;j<8;++j) { cc *= v[j]; o[j] = tanhf(cc); }
  float* dst = th + (size_t)token * Dc + lane * 8;
  *(float4*)dst     = make_float4(o[0],o[1],o[2],o[3]);
  *(float4*)(dst+4) = make_float4(o[4],o[5],o[6],o[7]);
  __syncthreads();
  int d = threadIdx.x;
  if (d < Dc) {
    const float* pp = th + ((size_t)b*Tc + c*TSF)*Dc + d;
    float s = 0.f;
    #pragma unroll
    for (int t=0;t<TSF;++t) s += pp[(size_t)t*Dc];
    partA[((size_t)b*NCF + c)*Dc + d] = s;
  }
}

// ---------- in-place exclusive prefix over 128 chunks: 1 wave per (b,d) ---
__global__ __launch_bounds__(512) void part_prefix(float* __restrict__ part)
{
  int pair = blockIdx.x * 8 + (threadIdx.x >> 6);   // 2048 (b,d) pairs
  int lane = threadIdx.x & 63;
  int b = pair >> 9, d = pair & 511;
  size_t i0 = ((size_t)b*NCF + 2*lane)*Dc + d;
  float v0 = part[i0];
  float v1 = part[i0 + Dc];
  float ps = v0 + v1;
  float incl = ps;
  #pragma unroll
  for (int off=1; off<64; off<<=1) {
    float t = __shfl_up(incl, off);
    if (lane >= off) incl += t;
  }
  float excl = incl - ps;
  part[i0]      = excl;
  part[i0 + Dc] = excl + v0;
}

// ---------- bd = cumsum_t(th); h = embed[x]*(1+bd); chunk sums + weighted -
__global__ __launch_bounds__(512) void bd_apply(
    const float* __restrict__ th, const float* __restrict__ partA,
    const int* __restrict__ x, const float* __restrict__ embed,
    float* __restrict__ h, float* __restrict__ partB,
    float* __restrict__ partW, const float* __restrict__ kvec)
{
  int c = blockIdx.x, b = blockIdx.y, d = threadIdx.x;
  float w0 = decay_w(kvec, 0);
  float acc = partA[((size_t)b*NCF + c)*Dc + d];   // exclusive prefix (th)
  float hsum = 0.f, psW = 0.f;
  #pragma unroll
  for (int t=0;t<TSF;++t) {
    int tt = c*TSF + t;
    size_t idx = ((size_t)b*Tc + tt)*Dc + d;
    acc += th[idx];
    int row = x[b*Tc + tt];
    float e = embed[(size_t)row*Dc + d];
    float hv = e * (1.0f + acc);
    h[idx] = hv;
    hsum += hv;
    psW = psW * w0 + hv;                           // Horner: sum w^(15-t) hv
  }
  partB[((size_t)b*NCF + c)*Dc + d] = hsum;        // raw chunk sum (h)
  partW[((size_t)b*NCF + c)*Dc + d] = psW;         // weighted (layer-0 w)
}

// ---------- fused: mag (LDS only) + geometric scan + LayerNorm -> bf16 ----
__global__ __launch_bounds__(512) void mag_scan_ln(
    const float* __restrict__ h, const float* __restrict__ part,
    const float* __restrict__ partW,
    const float* __restrict__ kvec, int l,
    const float* __restrict__ g, const float* __restrict__ bt,
    unsigned short* __restrict__ yb)
{
  __shared__ float redA[8][TSF];
  __shared__ float redB[8][TSF];
  __shared__ float mag[TSF], muS[TSF], rsS[TSF];
  int c = blockIdx.x, b = blockIdx.y, d = threadIdx.x;
  int lane = d & 63, wv = d >> 6;
  float acc = part[((size_t)b*NCF + c)*Dc + d];    // exclusive prefix (h)
  int t0 = c * TSF;
  const float* hbase = h + (size_t)b*Tc*Dc + d;
  float hp = (t0 > 0) ? hbase[(size_t)(t0-1)*Dc] : 0.f;
  float hv[TSF];
  #pragma unroll
  for (int t=0;t<TSF;++t) {
    hv[t] = hbase[(size_t)(t0+t)*Dc];
    acc += hv[t];
    float diff = acc - hp;
    hp = hv[t];
    float s = diff * diff;
    #pragma unroll
    for (int off=32; off; off>>=1) s += __shfl_down(s, off);
    if (!lane) redA[wv][t] = s;
  }
  float w = decay_w(kvec, l);
  float s = (c > 0) ? partW[((size_t)b*NCF + (c-1))*Dc + d] : 0.f;
  __syncthreads();
  if (d < TSF) {
    float m = 0.f;
    #pragma unroll
    for (int w2=0;w2<8;++w2) m += redA[w2][d];
    mag[d] = sqrtf(m);
  }
  __syncthreads();
  #pragma unroll
  for (int t=0;t<TSF;++t) {
    s = hv[t] + w * s;
    float cv = mag[t] * fabsf(s);
    hv[t] = cv;
    float s1 = cv, s2 = cv * cv;
    #pragma unroll
    for (int off=32; off; off>>=1) {
      s1 += __shfl_down(s1, off);
      s2 += __shfl_down(s2, off);
    }
    if (!lane) { redA[wv][t] = s1; redB[wv][t] = s2; }
  }
  __syncthreads();
  if (d < TSF) {
    float m1 = 0.f, m2 = 0.f;
    #pragma unroll
    for (int w2=0;w2<8;++w2) { m1 += redA[w2][d]; m2 += redB[w2][d]; }
    float mu = m1 * (1.f/Dc);
    float var = fmaxf(m2 * (1.f/Dc) - mu*mu, 0.f);
    muS[d] = mu;
    rsS[d] = rsqrtf(var + 1e-3f);
  }
  __syncthreads();
  float gv = g[l*Dc + d], bv = bt[l*Dc + d];
  unsigned short* yp = yb + ((size_t)b*Tc + t0)*Dc + d;
  #pragma unroll
  for (int t=0;t<TSF;++t)
    yp[(size_t)t*Dc] = f2bf((hv[t] - muS[t]) * rsS[t] * gv + bv);
}

// CH=4: (row>>1)&3 ; CH=8: row&7.
template<int CH> __device__ inline int swz(int row) {
  if constexpr (CH == 8) return row & 7;
  else return (row >> 1) & 3;
}

// ---------- GEMM1: dedicated 256x256 8-wave phase-split, ring-4 BK=32 ----
// R25-verified. Cb = bf16(gelu(A@Bt^T + bias)).
__global__ __launch_bounds__(512, 2) void mgemm1(
    const unsigned short* __restrict__ A,
    const unsigned short* __restrict__ Bt,
    const float* __restrict__ bias,
    unsigned short* __restrict__ Cb,
    int N, int K, int nrow)
{
  constexpr int TM = 256, TN = 256, BK = 32;
  constexpr int PA = 2, PB = 2;
  constexpr int ASTG = TM*BK, BSTG = TN*BK;
  __shared__ unsigned short As[4*ASTG];      // 4 x 16KB
  __shared__ unsigned short Bs[4*BSTG];      // 4 x 16KB
  int tid = threadIdx.x;
  int lane = tid & 63, w = tid >> 6;
  int wr = w >> 2, wc = w & 3;               // 2(M) x 4(N) wave grid
  int bid = blockIdx.x;
  int xcd = bid & 7, i = bid >> 3;
  int npx = nrow >> 3;
  int m0 = (xcd * npx + (i % npx)) * TM;
  int n0 = (i / npx) * TN;

  const unsigned short* ag[PA];
  const unsigned short* bg[PB];
  int aldst[PA], bldst[PB];
  #pragma unroll
  for (int p=0;p<PA;++p) {
    int ci = p*512 + tid;
    int row = ci >> 2, cp = ci & 3;
    int cg = cp ^ ((row >> 1) & 3);
    ag[p] = A + (size_t)(m0+row)*K + cg*8;
    aldst[p] = (p*512 + w*64)*8;
  }
  #pragma unroll
  for (int p=0;p<PB;++p) {
    int ci = p*512 + tid;
    int row = ci >> 2, cp = ci & 3;
    int cg = cp ^ ((row >> 1) & 3);
    bg[p] = Bt + (size_t)(n0+row)*K + cg*8;
    bldst[p] = (p*512 + w*64)*8;
  }

  int r = lane & 15, quad = lane >> 4;
  int sz = (quad ^ ((r >> 1) & 3)) * 8;      // swizzled chunk offset (shorts)
  int aoff[8], boff[4];
  #pragma unroll
  for (int fi=0; fi<8; ++fi)
    aoff[fi] = (wr*128 + fi*16 + r)*BK + sz;
  #pragma unroll
  for (int fj=0; fj<4; ++fj)
    boff[fj] = (wc*64 + fj*16 + r)*BK + sz;

  f32x4 acc[8][4];
  #pragma unroll
  for (int fi=0;fi<8;++fi)
    #pragma unroll
    for (int fj=0;fj<4;++fj)
      acc[fi][fj] = (f32x4){0.f,0.f,0.f,0.f};

  auto STAGE_A = [&](int t) {
    int kk = t * BK, sl = t & 3;
    #pragma unroll
    for (int p=0;p<PA;++p) gload_lds16(ag[p] + kk, &As[sl*ASTG + aldst[p]]);
  };
  auto STAGE_B = [&](int t) {
    int kk = t * BK, sl = t & 3;
    #pragma unroll
    for (int p=0;p<PB;++p) gload_lds16(bg[p] + kk, &Bs[sl*BSTG + bldst[p]]);
  };

  int nk = K / BK;                 // 16 for GEMM1
  STAGE_A(0); STAGE_B(0);
  STAGE_A(1); STAGE_B(1);
  STAGE_A(2); STAGE_B(2);

  for (int kt = 0; kt < nk; ++kt) {
    if (kt < nk-2)       wvm<8>();
    else if (kt == nk-2) wvm<4>();
    else                 wvm<0>();
    barrier_raw();
    int s = kt & 3;
    short8 bfr[4], af[4];
    #pragma unroll
    for (int fj=0;fj<4;++fj) bfr[fj] = *(const short8*)&Bs[s*BSTG + boff[fj]];
    #pragma unroll
    for (int fi=0;fi<4;++fi) af[fi] = *(const short8*)&As[s*ASTG + aoff[fi]];
    if (kt + 3 < nk) STAGE_A(kt + 3);
    __builtin_amdgcn_s_setprio(1);
    #pragma unroll
    for (int fi=0;fi<4;++fi)
      #pragma unroll
      for (int fj=0;fj<4;++fj)
        acc[fi][fj] = __builtin_amdgcn_mfma_f32_16x16x32_bf16(
            af[fi], bfr[fj], acc[fi][fj], 0, 0, 0);
    __builtin_amdgcn_s_setprio(0);
    barrier_raw();
    #pragma unroll
    for (int fi=0;fi<4;++fi) af[fi] = *(const short8*)&As[s*ASTG + aoff[4+fi]];
    if (kt + 3 < nk) STAGE_B(kt + 3);
    __builtin_amdgcn_s_setprio(1);
    #pragma unroll
    for (int fi=0;fi<4;++fi)
      #pragma unroll
      for (int fj=0;fj<4;++fj)
        acc[4+fi][fj] = __builtin_amdgcn_mfma_f32_16x16x32_bf16(
            af[fi], bfr[fj], acc[4+fi][fj], 0, 0, 0);
    __builtin_amdgcn_s_setprio(0);
  }

  #pragma unroll
  for (int fi=0;fi<8;++fi) {
    int rowb = m0 + wr*128 + fi*16 + quad*4;
    #pragma unroll
    for (int fj=0;fj<4;++fj) {
      int col = n0 + wc*64 + fj*16 + r;
      float bv = bias[col];
      #pragma unroll
      for (int reg=0;reg<4;++reg) {
        size_t idx = (size_t)(rowb + reg) * N + col;
        Cb[idx] = f2bf(gelu_f(acc[fi][fj][reg] + bv));
      }
    }
  }
}

// ---------- GEMM2: dedicated 128x64 BK=64, ring-3 + counted vmcnt --------
// R10 mgemm<1,128,64,64> body with ONE extra ring slot (72KB LDS, still
// 2 blocks/CU) and wvm<6> per step: lead-2 in time (~1200cy) covers the
// L3-resident stage latency (~500-900cy) that dbuf's 1-phase lead missed.
// WAR: STAGE(ki+2) writes slot (ki+2)%3 == (ki-1)%3, whose reads finished
// before barrier(ki). Ledger: at wait(ki) outstanding = tiles {ki,ki+1} =
// 12 loads -> vmcnt(6) drains ki, keeps ki+1 airborne.
__global__ __launch_bounds__(256) void mgemm2(
    const unsigned short* __restrict__ A,
    const unsigned short* __restrict__ Bt,
    const float* __restrict__ bias,
    float* __restrict__ C, unsigned short* __restrict__ Cb,
    float* __restrict__ part, float* __restrict__ partW,
    const float* __restrict__ kvec, int wl,
    int N, int K, int nrow)
{
  constexpr int TM = 128, TN = 64, BK = 64;
  constexpr int CH = 8;                      // BK/8
  constexpr int PA = 4, PB = 2;              // TM*CH/256, TN*CH/256
  constexpr int WM = 64, WN = 32;
  constexpr int AM = 4, AN = 2, NKH = 2;
  constexpr int ASTG = TM*BK, BSTG = TN*BK;  // 8192 / 4096 shorts
  __shared__ unsigned short As[3*ASTG];      // 48KB
  __shared__ unsigned short Bs[3*BSTG];      // 24KB
  int tid = threadIdx.x;
  int lane = tid & 63, w = tid >> 6;
  int wr = w >> 1, wc = w & 1;
  int bid = blockIdx.x;
  int xcd = bid & 7, i = bid >> 3;
  int npx = nrow >> 3;
  int m0 = (xcd * npx + (i % npx)) * TM;
  int n0 = (i / npx) * TN;

  const unsigned short* ag[PA];
  const unsigned short* bg[PB];
  int aldst[PA], bldst[PB];
  #pragma unroll
  for (int p=0;p<PA;++p) {
    int ci = p*256 + tid;
    int row = ci / CH, cp = ci % CH;
    int cg = cp ^ (row & 7);
    ag[p] = A + (size_t)(m0+row)*K + cg*8;
    aldst[p] = (p*256 + w*64)*8;
  }
  #pragma unroll
  for (int p=0;p<PB;++p) {
    int ci = p*256 + tid;
    int row = ci / CH, cp = ci % CH;
    int cg = cp ^ (row & 7);
    bg[p] = Bt + (size_t)(n0+row)*K + cg*8;
    bldst[p] = (p*256 + w*64)*8;
  }

  int r = lane & 15, quad = lane >> 4;
  int aoff[NKH][AM], boff[NKH][AN];
  #pragma unroll
  for (int kh=0;kh<NKH;++kh) {
    int cb = kh*4 + quad;
    #pragma unroll
    for (int i2=0;i2<AM;++i2)
      aoff[kh][i2] = (wr*WM + i2*16 + r)*BK + ((cb ^ (r & 7)) & 7)*8;
    #pragma unroll
    for (int j=0;j<AN;++j)
      boff[kh][j] = (wc*WN + j*16 + r)*BK + ((cb ^ (r & 7)) & 7)*8;
  }

  f32x4 acc[AM][AN];
  #pragma unroll
  for (int i2=0;i2<AM;++i2)
    #pragma unroll
    for (int j=0;j<AN;++j)
      acc[i2][j] = (f32x4){0.f,0.f,0.f,0.f};

  auto STAGE = [&](int t) {
    int kk = t * BK;
    int sl = t % 3;
    #pragma unroll
    for (int p=0;p<PA;++p) gload_lds16(ag[p] + kk, &As[sl*ASTG + aldst[p]]);
    #pragma unroll
    for (int p=0;p<PB;++p) gload_lds16(bg[p] + kk, &Bs[sl*BSTG + bldst[p]]);
  };

  int nk = K / BK;                 // 32 for GEMM2
  STAGE(0); STAGE(1);              // lead-2

  for (int ki = 0; ki < nk; ++ki) {
    if (ki + 1 < nk) wvm<6>();
    else             wvm<0>();
    barrier_raw();
    if (ki + 2 < nk) STAGE(ki + 2);
    int cur = ki % 3;
    #pragma unroll
    for (int kh=0;kh<NKH;++kh) {
      short8 af[AM], bfr[AN];
      #pragma unroll
      for (int i2=0;i2<AM;++i2) af[i2] = *(const short8*)&As[cur*ASTG + aoff[kh][i2]];
      #pragma unroll
      for (int j=0;j<AN;++j) bfr[j] = *(const short8*)&Bs[cur*BSTG + boff[kh][j]];
      __builtin_amdgcn_s_setprio(1);
      #pragma unroll
      for (int i2=0;i2<AM;++i2)
        #pragma unroll
        for (int j=0;j<AN;++j)
          acc[i2][j] = __builtin_amdgcn_mfma_f32_16x16x32_bf16(af[i2], bfr[j], acc[i2][j], 0, 0, 0);
      __builtin_amdgcn_s_setprio(0);
    }
  }

  // weighted-partial setup (next layer's decay), row-in-chunk = quad*4+reg
  float wnext = 0.f, invw = 0.f, pwbase = 0.f;
  if (partW) {
    wnext = decay_w(kvec, wl);
    invw = 1.0f / wnext;
    pwbase = 1.0f;
    for (int q = 0; q < 15 - quad*4; ++q) pwbase *= wnext;  // w^(15-quad*4)
  }

  #pragma unroll
  for (int i2=0;i2<AM;++i2) {
    int rowb = m0 + wr*WM + i2*16 + quad*4;
    #pragma unroll
    for (int j=0;j<AN;++j) {
      int col = n0 + wc*WN + j*16 + r;
      float bv = bias[col];
      float ps = 0.f, psW = 0.f, pw = pwbase;
      #pragma unroll
      for (int reg=0;reg<4;++reg) {
        size_t idx = (size_t)(rowb + reg) * N + col;
        float z = acc[i2][j][reg] + bv;
        float hv = C[idx] + z;
        C[idx] = hv;
        ps += hv;
        if (partW) { psW += pw * hv; pw *= invw; }
        if (Cb) Cb[idx] = f2bf(hv);
      }
      if (part) {
        ps += __shfl_xor(ps, 16);
        ps += __shfl_xor(ps, 32);
        if (partW) {
          psW += __shfl_xor(psW, 16);
          psW += __shfl_xor(psW, 32);
        }
        if (quad == 0) {
          int chunk = (m0 + wr*WM + i2*16) >> 4;   // TSF=16
          part[(size_t)chunk * N + col] = ps;
          if (partW) partW[(size_t)chunk * N + col] = psW;
        }
      }
    }
  }
}

// ---------- bf16 MFMA GEMM, dbuf LDS (vocab head only, EPI=2: C=z) -------
template<int EPI, int TM, int TN, int BK>
__global__ __launch_bounds__(256) void mgemm(
    const unsigned short* __restrict__ A,
    const unsigned short* __restrict__ Bt,
    const float* __restrict__ bias,
    float* __restrict__ C, unsigned short* __restrict__ Cb,
    float* __restrict__ part, float* __restrict__ partW,
    const float* __restrict__ kvec, int wl,
    int N, int K, int nrow)
{
  constexpr int CH = BK / 8;
  constexpr int PA = TM*CH/256, PB = TN*CH/256;
  constexpr int WM = TM/2, WN = TN/2;
  constexpr int AM = WM/16, AN = WN/16;
  constexpr int NKH = BK/32;
  constexpr int ASTG = TM*BK, BSTG = TN*BK;
  __shared__ unsigned short As[2*ASTG];
  __shared__ unsigned short Bs[2*BSTG];
  int tid = threadIdx.x;
  int lane = tid & 63, w = tid >> 6;
  int wr = w >> 1, wc = w & 1;
  int bid = blockIdx.x;
  int xcd = bid & 7, i = bid >> 3;
  int npx = nrow >> 3;
  int m0 = (xcd * npx + (i % npx)) * TM;
  int n0 = (i / npx) * TN;

  const unsigned short* ag[PA];
  const unsigned short* bg[PB];
  int aldst[PA], bldst[PB];
  #pragma unroll
  for (int p=0;p<PA;++p) {
    int ci = p*256 + tid;
    int row = ci / CH, cp = ci % CH;
    int cg = cp ^ swz<CH>(row);
    ag[p] = A + (size_t)(m0+row)*K + cg*8;
    aldst[p] = (p*256 + w*64)*8;
  }
  #pragma unroll
  for (int p=0;p<PB;++p) {
    int ci = p*256 + tid;
    int row = ci / CH, cp = ci % CH;
    int cg = cp ^ swz<CH>(row);
    bg[p] = Bt + (size_t)(n0+row)*K + cg*8;
    bldst[p] = (p*256 + w*64)*8;
  }

  int r = lane & 15, quad = lane >> 4;
  int aoff[NKH][AM], boff[NKH][AN];
  #pragma unroll
  for (int kh=0;kh<NKH;++kh) {
    int cb = kh*4 + quad;
    #pragma unroll
    for (int i2=0;i2<AM;++i2)
      aoff[kh][i2] = (wr*WM + i2*16 + r)*BK + ((cb ^ swz<CH>(r)) & (CH-1))*8;
    #pragma unroll
    for (int j=0;j<AN;++j)
      boff[kh][j] = (wc*WN + j*16 + r)*BK + ((cb ^ swz<CH>(r)) & (CH-1))*8;
  }

  f32x4 acc[AM][AN];
  #pragma unroll
  for (int i2=0;i2<AM;++i2)
    #pragma unroll
    for (int j=0;j<AN;++j)
      acc[i2][j] = (f32x4){0.f,0.f,0.f,0.f};

  #pragma unroll
  for (int p=0;p<PA;++p) gload_lds16(ag[p], &As[aldst[p]]);
  #pragma unroll
  for (int p=0;p<PB;++p) gload_lds16(bg[p], &Bs[bldst[p]]);

  int nk = K / BK;
  for (int ki = 0; ki < nk; ++ki) {
    __syncthreads();
    int cur = ki & 1, nxt = cur ^ 1;
    if (ki + 1 < nk) {
      int kk = (ki + 1) * BK;
      #pragma unroll
      for (int p=0;p<PA;++p) gload_lds16(ag[p] + kk, &As[nxt*ASTG + aldst[p]]);
      #pragma unroll
      for (int p=0;p<PB;++p) gload_lds16(bg[p] + kk, &Bs[nxt*BSTG + bldst[p]]);
    }
    #pragma unroll
    for (int kh=0;kh<NKH;++kh) {
      short8 af[AM], bfr[AN];
      #pragma unroll
      for (int i2=0;i2<AM;++i2) af[i2] = *(const short8*)&As[cur*ASTG + aoff[kh][i2]];
      #pragma unroll
      for (int j=0;j<AN;++j) bfr[j] = *(const short8*)&Bs[cur*BSTG + boff[kh][j]];
      #pragma unroll
      for (int i2=0;i2<AM;++i2)
        #pragma unroll
        for (int j=0;j<AN;++j)
          acc[i2][j] = __builtin_amdgcn_mfma_f32_16x16x32_bf16(af[i2], bfr[j], acc[i2][j], 0, 0, 0);
    }
  }

  #pragma unroll
  for (int i2=0;i2<AM;++i2) {
    int rowb = m0 + wr*WM + i2*16 + quad*4;
    #pragma unroll
    for (int j=0;j<AN;++j) {
      int col = n0 + wc*WN + j*16 + r;
      #pragma unroll
      for (int reg=0;reg<4;++reg) {
        size_t idx = (size_t)(rowb + reg) * N + col;
        C[idx] = acc[i2][j][reg];
      }
    }
  }
}

extern "C" void kernel_launch(void* const* d_in, const int* in_sizes, int n_in,
                              void* d_out, int out_size, void* d_ws, size_t ws_size,
                              hipStream_t stream) {
  const int*   x     = (const int*)  d_in[0];
  const float* embed = (const float*)d_in[1];
  const float* kvec  = (const float*)d_in[2];
  const float* g     = (const float*)d_in[3];
  const float* bt    = (const float*)d_in[4];
  const float* W1    = (const float*)d_in[5];
  const float* b1    = (const float*)d_in[6];
  const float* W2    = (const float*)d_in[7];
  const float* b2    = (const float*)d_in[8];
  float* out = (float*)d_out;

  const size_t NTD = (size_t)Bc * Tc * Dc;   // 4,194,304
  const size_t NTH = (size_t)Bc * Tc * Hc;   // 16,777,216
  char* wsb = (char*)d_ws;
  float* h      = (float*)wsb;                wsb += NTD*4;               // 16MB
  float* tmpA   = (float*)wsb;                wsb += NTD*4;               // 16MB (th)
  float* partA  = (float*)wsb;                wsb += (size_t)Bc*NCF*Dc*4; // 1MB
  float* partB  = (float*)wsb;                wsb += (size_t)Bc*NCF*Dc*4; // 1MB
  float* partW  = (float*)wsb;                wsb += (size_t)Bc*NCF*Dc*4; // 1MB
  unsigned short* yb   = (unsigned short*)wsb; wsb += NTD*2;              // 8MB
  unsigned short* a1b  = (unsigned short*)wsb; wsb += NTH*2;              // 32MB
  unsigned short* hb   = (unsigned short*)wsb; wsb += NTD*2;              // 8MB
  unsigned short* W1t  = (unsigned short*)wsb; wsb += (size_t)3*Dc*Hc*2;  // 6MB
  unsigned short* W2t  = (unsigned short*)wsb; wsb += (size_t)3*Dc*Hc*2;  // 6MB
  unsigned short* emb  = (unsigned short*)wsb; wsb += (size_t)Vc*Dc*2;

  // merged weight prep (1 dispatch); emb branch: 128 blocks x 256thr x 4el
  wprep<<<dim3(6144 + (Vc*Dc)/1024), 256, 0, stream>>>(
      W1, W1t, W2, W2t, embed, emb);

  // prologue
  embed_part<<<dim3(NCF, Bc), 1024, 0, stream>>>(x, embed, tmpA, partA);
  part_prefix<<<dim3(256), 512, 0, stream>>>(partA);
  bd_apply<<<dim3(NCF, Bc), 512, 0, stream>>>(tmpA, partA, x, embed, h,
                                              partB, partW, kvec);
  part_prefix<<<dim3(256), 512, 0, stream>>>(partB);

  for (int l = 0; l < 3; ++l) {
    mag_scan_ln<<<dim3(NCF, Bc), 512, 0, stream>>>(h, partB, partW, kvec, l,
                                                   g, bt, yb);
    // z = gelu(y @ W1 + b1): M=8192 N=2048 K=512
    // dedicated 256x256 8-wave phase-split, ring-4 lead-3, 256 blocks
    mgemm1<<<dim3(256), 512, 0, stream>>>(
        yb, W1t + (size_t)l*Hc*Dc, b1 + (size_t)l*Hc, a1b, Hc, Dc, 32);
    // h += z @ W2 + b2 (+ raw & weighted chunk partials for layer l+1)
    // M=8192 N=512 K=2048; dedicated 128x64 BK=64 ring-3 counted-vmcnt
    mgemm2<<<dim3(64*(Dc/64)), 256, 0, stream>>>(
        a1b, W2t + (size_t)l*Dc*Hc, b2 + (size_t)l*Dc, h,
        (l == 2) ? hb : nullptr,
        (l < 2) ? partB : nullptr, (l < 2) ? partW : nullptr, kvec, l + 1,
        Dc, Hc, 64);
    if (l < 2) part_prefix<<<dim3(256), 512, 0, stream>>>(partB);
  }
  // out = h @ embed^T: M=8192 N=256 K=512; 64x64 BK=32 dbuf, nrow=128
  mgemm<2,64,64,32><<<dim3(128*(Vc/64)), 256, 0, stream>>>(
      hb, emb, nullptr, out, nullptr, nullptr, nullptr, kvec, 0,
      Vc, Dc, 128);
}

// Round 12
// 392.844 us; speedup vs baseline: 1.0164x; 1.0164x over previous
//
#include <hip/hip_runtime.h>
#include <math.h>

// DeltaLM: B=4 T=2048 D=512 H=2048 L=3 V=256
// decay einsum == geometric scan S[i]=h[i]+w*S[i-1], w=exp(-softplus(k)).
// Round 28: R27's ring-3 counted-vmcnt GEMM2 = 44.0us (neutral vs 43.2
// dbuf, inside the pre-committed band) -> L3-latency theory falsified;
// SIX schedule families all land GEMM2 at 43-50us with all pipes idle.
// GEMM2 arm declared exhausted. This round: revert to the R26 champion
// (390.8us best): mgemm1 (dedicated 8-wave 256^2) + mgemm<1,128,64,64>
// dbuf GEMM2 + 3-term erf + vectorized wprep. No dead instantiations
// (rule #19). Expect reproduction ~390; if confirmed, structure-floor
// stands and remaining mass is memory-bound small kernels + gaps.

constexpr int Bc = 4, Tc = 2048, Dc = 512, Hc = 2048, Vc = 256;
constexpr int TSF = 16, NCF = 128;

typedef __attribute__((ext_vector_type(8))) short short8;
typedef __attribute__((ext_vector_type(4))) float f32x4;

__device__ inline unsigned short f2bf(float f) {  // RNE fp32->bf16
  unsigned int u = __float_as_uint(f);
  u += 0x7fffu + ((u >> 16) & 1u);
  return (unsigned short)(u >> 16);
}

__device__ inline void gload_lds16(const void* g, void* l) {
  __builtin_amdgcn_global_load_lds(
      (const __attribute__((address_space(1))) void*)g,
      (__attribute__((address_space(3))) void*)l, 16, 0, 0);
}

template<int N> __device__ inline void wvm() {
  if constexpr (N == 0)      asm volatile("s_waitcnt vmcnt(0)" ::: "memory");
  else if constexpr (N == 4) asm volatile("s_waitcnt vmcnt(4)" ::: "memory");
  else if constexpr (N == 8) asm volatile("s_waitcnt vmcnt(8)" ::: "memory");
  else static_assert(N == 0, "unsupported vmcnt");
}
__device__ inline void barrier_raw() {
  asm volatile("s_barrier" ::: "memory");
}

// gelu(z) = 0.5 z (1+erf(z/sqrt2)); erf via A&S 7.1.25, |eps|<=2.5e-5
// (bf16 rel eps ~2e-3 -> approximation error invisible after f2bf)
__device__ inline float gelu_f(float z) {
  float x = z * 0.707106781186547524f;
  float ax = fabsf(x);
  float t = __builtin_amdgcn_rcpf(fmaf(0.47047f, ax, 1.0f));
  float poly = t*(0.3480242f + t*(-0.0958798f + t*0.7478556f));
  float er = 1.0f - poly * __expf(-ax*ax);
  er = copysignf(er, x);
  return 0.5f * z * (1.0f + er);
}

__device__ inline float decay_w(const float* kvec, int l) {
  float kk = kvec[l];
  float sp = kk > 0.f ? kk + log1pf(expf(-kk)) : log1pf(expf(kk));
  return expf(-sp);
}

// ---------- merged weight prep: W1t, W2t (transpose->bf16) + emb ----------
__device__ inline void tr32(const float* Wl, unsigned short* Wtl,
                            int R, int C, int c0, int r0, int tid,
                            float (*tile)[33]) {
  int tx = tid & 31, ty = tid >> 5;
  for (int i = ty; i < 32; i += 8)
    tile[i][tx] = Wl[(size_t)(r0+i)*C + (c0+tx)];
  __syncthreads();
  int rx = tid & 7, ry = tid >> 3;   // ry: c-row 0..31, rx*4: r offset
  ushort4 o;
  o.x = f2bf(tile[rx*4+0][ry]);
  o.y = f2bf(tile[rx*4+1][ry]);
  o.z = f2bf(tile[rx*4+2][ry]);
  o.w = f2bf(tile[rx*4+3][ry]);
  *(ushort4*)&Wtl[(size_t)(c0+ry)*R + (r0 + rx*4)] = o;
}

__global__ __launch_bounds__(256) void wprep(
    const float* __restrict__ W1, unsigned short* __restrict__ W1t,
    const float* __restrict__ W2, unsigned short* __restrict__ W2t,
    const float* __restrict__ embed, unsigned short* __restrict__ emb)
{
  __shared__ float tile[32][33];
  int bid = blockIdx.x, tid = threadIdx.x;
  if (bid < 3072) {            // W1: (L, Dc, Hc) -> (L, Hc, Dc) bf16
    int l = bid >> 10, rem = bid & 1023;
    int cx = rem & 63, ry = rem >> 6;      // C/32=64, R/32=16
    tr32(W1 + (size_t)l*Dc*Hc, W1t + (size_t)l*Dc*Hc, Dc, Hc,
         cx*32, ry*32, tid, tile);
  } else if (bid < 6144) {     // W2: (L, Hc, Dc) -> (L, Dc, Hc) bf16
    int b2 = bid - 3072;
    int l = b2 >> 10, rem = b2 & 1023;
    int cx = rem & 15, ry = rem >> 4;      // C/32=16, R/32=64
    tr32(W2 + (size_t)l*Hc*Dc, W2t + (size_t)l*Hc*Dc, Hc, Dc,
         cx*32, ry*32, tid, tile);
  } else {                     // emb: fp32 -> bf16, 4 elems/thread
    int i = ((bid - 6144)*256 + tid) * 4;
    if (i < Vc*Dc) {
      float4 v = *(const float4*)&embed[i];
      ushort4 o;
      o.x = f2bf(v.x); o.y = f2bf(v.y); o.z = f2bf(v.z); o.w = f2bf(v.w);
      *(ushort4*)&emb[i] = o;
    }
  }
}

// ---------- embed gather + cumprod + tanh + chunk sums (fused) ----------
__global__ __launch_bounds__(1024) void embed_part(
    const int* __restrict__ x, const float* __restrict__ embed,
    float* __restrict__ th, float* __restrict__ partA)
{
  int c = blockIdx.x, b = blockIdx.y;
  int wv = threadIdx.x >> 6, lane = threadIdx.x & 63;
  int token = b*Tc + c*TSF + wv;
  int row = x[token];
  const float* e = embed + (size_t)row * Dc + lane * 8;
  float v[8];
  {
    float4 a = *(const float4*)e;
    float4 bb = *(const float4*)(e + 4);
    v[0]=a.x; v[1]=a.y; v[2]=a.z; v[3]=a.w;
    v[4]=bb.x; v[5]=bb.y; v[6]=bb.z; v[7]=bb.w;
  }
  float p = v[0];
  #pragma unroll
  for (int j=1;j<8;++j) p *= v[j];
  float incl = p;
  #pragma unroll
  for (int off=1; off<64; off<<=1) {
    float t = __shfl_up(incl, off);
    if (lane >= off) incl *= t;
  }
  float excl = __shfl_up(incl, 1);
  if (lane == 0) excl = 1.0f;
  float cc = excl;
  float o[8];
  #pragma unroll
  for (int j=0;j<8;++j) { cc *= v[j]; o[j] = tanhf(cc); }
  float* dst = th + (size_t)token * Dc + lane * 8;
  *(float4*)dst     = make_float4(o[0],o[1],o[2],o[3]);
  *(float4*)(dst+4) = make_float4(o[4],o[5],o[6],o[7]);
  __syncthreads();
  int d = threadIdx.x;
  if (d < Dc) {
    const float* pp = th + ((size_t)b*Tc + c*TSF)*Dc + d;
    float s = 0.f;
    #pragma unroll
    for (int t=0;t<TSF;++t) s += pp[(size_t)t*Dc];
    partA[((size_t)b*NCF + c)*Dc + d] = s;
  }
}

// ---------- in-place exclusive prefix over 128 chunks: 1 wave per (b,d) ---
__global__ __launch_bounds__(512) void part_prefix(float* __restrict__ part)
{
  int pair = blockIdx.x * 8 + (threadIdx.x >> 6);   // 2048 (b,d) pairs
  int lane = threadIdx.x & 63;
  int b = pair >> 9, d = pair & 511;
  size_t i0 = ((size_t)b*NCF + 2*lane)*Dc + d;
  float v0 = part[i0];
  float v1 = part[i0 + Dc];
  float ps = v0 + v1;
  float incl = ps;
  #pragma unroll
  for (int off=1; off<64; off<<=1) {
    float t = __shfl_up(incl, off);
    if (lane >= off) incl += t;
  }
  float excl = incl - ps;
  part[i0]      = excl;
  part[i0 + Dc] = excl + v0;
}

// ---------- bd = cumsum_t(th); h = embed[x]*(1+bd); chunk sums + weighted -
__global__ __launch_bounds__(512) void bd_apply(
    const float* __restrict__ th, const float* __restrict__ partA,
    const int* __restrict__ x, const float* __restrict__ embed,
    float* __restrict__ h, float* __restrict__ partB,
    float* __restrict__ partW, const float* __restrict__ kvec)
{
  int c = blockIdx.x, b = blockIdx.y, d = threadIdx.x;
  float w0 = decay_w(kvec, 0);
  float acc = partA[((size_t)b*NCF + c)*Dc + d];   // exclusive prefix (th)
  float hsum = 0.f, psW = 0.f;
  #pragma unroll
  for (int t=0;t<TSF;++t) {
    int tt = c*TSF + t;
    size_t idx = ((size_t)b*Tc + tt)*Dc + d;
    acc += th[idx];
    int row = x[b*Tc + tt];
    float e = embed[(size_t)row*Dc + d];
    float hv = e * (1.0f + acc);
    h[idx] = hv;
    hsum += hv;
    psW = psW * w0 + hv;                           // Horner: sum w^(15-t) hv
  }
  partB[((size_t)b*NCF + c)*Dc + d] = hsum;        // raw chunk sum (h)
  partW[((size_t)b*NCF + c)*Dc + d] = psW;         // weighted (layer-0 w)
}

// ---------- fused: mag (LDS only) + geometric scan + LayerNorm -> bf16 ----
__global__ __launch_bounds__(512) void mag_scan_ln(
    const float* __restrict__ h, const float* __restrict__ part,
    const float* __restrict__ partW,
    const float* __restrict__ kvec, int l,
    const float* __restrict__ g, const float* __restrict__ bt,
    unsigned short* __restrict__ yb)
{
  __shared__ float redA[8][TSF];
  __shared__ float redB[8][TSF];
  __shared__ float mag[TSF], muS[TSF], rsS[TSF];
  int c = blockIdx.x, b = blockIdx.y, d = threadIdx.x;
  int lane = d & 63, wv = d >> 6;
  float acc = part[((size_t)b*NCF + c)*Dc + d];    // exclusive prefix (h)
  int t0 = c * TSF;
  const float* hbase = h + (size_t)b*Tc*Dc + d;
  float hp = (t0 > 0) ? hbase[(size_t)(t0-1)*Dc] : 0.f;
  float hv[TSF];
  #pragma unroll
  for (int t=0;t<TSF;++t) {
    hv[t] = hbase[(size_t)(t0+t)*Dc];
    acc += hv[t];
    float diff = acc - hp;
    hp = hv[t];
    float s = diff * diff;
    #pragma unroll
    for (int off=32; off; off>>=1) s += __shfl_down(s, off);
    if (!lane) redA[wv][t] = s;
  }
  float w = decay_w(kvec, l);
  float s = (c > 0) ? partW[((size_t)b*NCF + (c-1))*Dc + d] : 0.f;
  __syncthreads();
  if (d < TSF) {
    float m = 0.f;
    #pragma unroll
    for (int w2=0;w2<8;++w2) m += redA[w2][d];
    mag[d] = sqrtf(m);
  }
  __syncthreads();
  #pragma unroll
  for (int t=0;t<TSF;++t) {
    s = hv[t] + w * s;
    float cv = mag[t] * fabsf(s);
    hv[t] = cv;
    float s1 = cv, s2 = cv * cv;
    #pragma unroll
    for (int off=32; off; off>>=1) {
      s1 += __shfl_down(s1, off);
      s2 += __shfl_down(s2, off);
    }
    if (!lane) { redA[wv][t] = s1; redB[wv][t] = s2; }
  }
  __syncthreads();
  if (d < TSF) {
    float m1 = 0.f, m2 = 0.f;
    #pragma unroll
    for (int w2=0;w2<8;++w2) { m1 += redA[w2][d]; m2 += redB[w2][d]; }
    float mu = m1 * (1.f/Dc);
    float var = fmaxf(m2 * (1.f/Dc) - mu*mu, 0.f);
    muS[d] = mu;
    rsS[d] = rsqrtf(var + 1e-3f);
  }
  __syncthreads();
  float gv = g[l*Dc + d], bv = bt[l*Dc + d];
  unsigned short* yp = yb + ((size_t)b*Tc + t0)*Dc + d;
  #pragma unroll
  for (int t=0;t<TSF;++t)
    yp[(size_t)t*Dc] = f2bf((hv[t] - muS[t]) * rsS[t] * gv + bv);
}

// CH=4: (row>>1)&3 ; CH=8: row&7.
template<int CH> __device__ inline int swz(int row) {
  if constexpr (CH == 8) return row & 7;
  else return (row >> 1) & 3;
}

// ---------- GEMM1: dedicated 256x256 8-wave phase-split, ring-4 BK=32 ----
// R25-verified. Cb = bf16(gelu(A@Bt^T + bias)).
__global__ __launch_bounds__(512, 2) void mgemm1(
    const unsigned short* __restrict__ A,
    const unsigned short* __restrict__ Bt,
    const float* __restrict__ bias,
    unsigned short* __restrict__ Cb,
    int N, int K, int nrow)
{
  constexpr int TM = 256, TN = 256, BK = 32;
  constexpr int PA = 2, PB = 2;
  constexpr int ASTG = TM*BK, BSTG = TN*BK;
  __shared__ unsigned short As[4*ASTG];      // 4 x 16KB
  __shared__ unsigned short Bs[4*BSTG];      // 4 x 16KB
  int tid = threadIdx.x;
  int lane = tid & 63, w = tid >> 6;
  int wr = w >> 2, wc = w & 3;               // 2(M) x 4(N) wave grid
  int bid = blockIdx.x;
  int xcd = bid & 7, i = bid >> 3;
  int npx = nrow >> 3;
  int m0 = (xcd * npx + (i % npx)) * TM;
  int n0 = (i / npx) * TN;

  const unsigned short* ag[PA];
  const unsigned short* bg[PB];
  int aldst[PA], bldst[PB];
  #pragma unroll
  for (int p=0;p<PA;++p) {
    int ci = p*512 + tid;
    int row = ci >> 2, cp = ci & 3;
    int cg = cp ^ ((row >> 1) & 3);
    ag[p] = A + (size_t)(m0+row)*K + cg*8;
    aldst[p] = (p*512 + w*64)*8;
  }
  #pragma unroll
  for (int p=0;p<PB;++p) {
    int ci = p*512 + tid;
    int row = ci >> 2, cp = ci & 3;
    int cg = cp ^ ((row >> 1) & 3);
    bg[p] = Bt + (size_t)(n0+row)*K + cg*8;
    bldst[p] = (p*512 + w*64)*8;
  }

  int r = lane & 15, quad = lane >> 4;
  int sz = (quad ^ ((r >> 1) & 3)) * 8;      // swizzled chunk offset (shorts)
  int aoff[8], boff[4];
  #pragma unroll
  for (int fi=0; fi<8; ++fi)
    aoff[fi] = (wr*128 + fi*16 + r)*BK + sz;
  #pragma unroll
  for (int fj=0; fj<4; ++fj)
    boff[fj] = (wc*64 + fj*16 + r)*BK + sz;

  f32x4 acc[8][4];
  #pragma unroll
  for (int fi=0;fi<8;++fi)
    #pragma unroll
    for (int fj=0;fj<4;++fj)
      acc[fi][fj] = (f32x4){0.f,0.f,0.f,0.f};

  auto STAGE_A = [&](int t) {
    int kk = t * BK, sl = t & 3;
    #pragma unroll
    for (int p=0;p<PA;++p) gload_lds16(ag[p] + kk, &As[sl*ASTG + aldst[p]]);
  };
  auto STAGE_B = [&](int t) {
    int kk = t * BK, sl = t & 3;
    #pragma unroll
    for (int p=0;p<PB;++p) gload_lds16(bg[p] + kk, &Bs[sl*BSTG + bldst[p]]);
  };

  int nk = K / BK;                 // 16 for GEMM1
  STAGE_A(0); STAGE_B(0);
  STAGE_A(1); STAGE_B(1);
  STAGE_A(2); STAGE_B(2);

  for (int kt = 0; kt < nk; ++kt) {
    if (kt < nk-2)       wvm<8>();
    else if (kt == nk-2) wvm<4>();
    else                 wvm<0>();
    barrier_raw();
    int s = kt & 3;
    short8 bfr[4], af[4];
    #pragma unroll
    for (int fj=0;fj<4;++fj) bfr[fj] = *(const short8*)&Bs[s*BSTG + boff[fj]];
    #pragma unroll
    for (int fi=0;fi<4;++fi) af[fi] = *(const short8*)&As[s*ASTG + aoff[fi]];
    if (kt + 3 < nk) STAGE_A(kt + 3);
    __builtin_amdgcn_s_setprio(1);
    #pragma unroll
    for (int fi=0;fi<4;++fi)
      #pragma unroll
      for (int fj=0;fj<4;++fj)
        acc[fi][fj] = __builtin_amdgcn_mfma_f32_16x16x32_bf16(
            af[fi], bfr[fj], acc[fi][fj], 0, 0, 0);
    __builtin_amdgcn_s_setprio(0);
    barrier_raw();
    #pragma unroll
    for (int fi=0;fi<4;++fi) af[fi] = *(const short8*)&As[s*ASTG + aoff[4+fi]];
    if (kt + 3 < nk) STAGE_B(kt + 3);
    __builtin_amdgcn_s_setprio(1);
    #pragma unroll
    for (int fi=0;fi<4;++fi)
      #pragma unroll
      for (int fj=0;fj<4;++fj)
        acc[4+fi][fj] = __builtin_amdgcn_mfma_f32_16x16x32_bf16(
            af[fi], bfr[fj], acc[4+fi][fj], 0, 0, 0);
    __builtin_amdgcn_s_setprio(0);
  }

  #pragma unroll
  for (int fi=0;fi<8;++fi) {
    int rowb = m0 + wr*128 + fi*16 + quad*4;
    #pragma unroll
    for (int fj=0;fj<4;++fj) {
      int col = n0 + wc*64 + fj*16 + r;
      float bv = bias[col];
      #pragma unroll
      for (int reg=0;reg<4;++reg) {
        size_t idx = (size_t)(rowb + reg) * N + col;
        Cb[idx] = f2bf(gelu_f(acc[fi][fj][reg] + bv));
      }
    }
  }
}

// ---------- bf16 MFMA GEMM, dbuf LDS, 1 barrier/K-step, XCD supertiles ----
// EPI 1: C+=z+bias (+ raw and weighted chunk partials via butterfly,
// opt Cb mirror); EPI 2: C=z.
template<int EPI, int TM, int TN, int BK>
__global__ __launch_bounds__(256) void mgemm(
    const unsigned short* __restrict__ A,
    const unsigned short* __restrict__ Bt,
    const float* __restrict__ bias,
    float* __restrict__ C, unsigned short* __restrict__ Cb,
    float* __restrict__ part, float* __restrict__ partW,
    const float* __restrict__ kvec, int wl,
    int N, int K, int nrow)
{
  constexpr int CH = BK / 8;
  constexpr int PA = TM*CH/256, PB = TN*CH/256;
  constexpr int WM = TM/2, WN = TN/2;
  constexpr int AM = WM/16, AN = WN/16;
  constexpr int NKH = BK/32;
  constexpr int ASTG = TM*BK, BSTG = TN*BK;
  __shared__ unsigned short As[2*ASTG];
  __shared__ unsigned short Bs[2*BSTG];
  int tid = threadIdx.x;
  int lane = tid & 63, w = tid >> 6;
  int wr = w >> 1, wc = w & 1;
  int bid = blockIdx.x;
  int xcd = bid & 7, i = bid >> 3;
  int npx = nrow >> 3;
  int m0 = (xcd * npx + (i % npx)) * TM;
  int n0 = (i / npx) * TN;

  const unsigned short* ag[PA];
  const unsigned short* bg[PB];
  int aldst[PA], bldst[PB];
  #pragma unroll
  for (int p=0;p<PA;++p) {
    int ci = p*256 + tid;
    int row = ci / CH, cp = ci % CH;
    int cg = cp ^ swz<CH>(row);
    ag[p] = A + (size_t)(m0+row)*K + cg*8;
    aldst[p] = (p*256 + w*64)*8;
  }
  #pragma unroll
  for (int p=0;p<PB;++p) {
    int ci = p*256 + tid;
    int row = ci / CH, cp = ci % CH;
    int cg = cp ^ swz<CH>(row);
    bg[p] = Bt + (size_t)(n0+row)*K + cg*8;
    bldst[p] = (p*256 + w*64)*8;
  }

  int r = lane & 15, quad = lane >> 4;
  int aoff[NKH][AM], boff[NKH][AN];
  #pragma unroll
  for (int kh=0;kh<NKH;++kh) {
    int cb = kh*4 + quad;
    #pragma unroll
    for (int i2=0;i2<AM;++i2)
      aoff[kh][i2] = (wr*WM + i2*16 + r)*BK + ((cb ^ swz<CH>(r)) & (CH-1))*8;
    #pragma unroll
    for (int j=0;j<AN;++j)
      boff[kh][j] = (wc*WN + j*16 + r)*BK + ((cb ^ swz<CH>(r)) & (CH-1))*8;
  }

  f32x4 acc[AM][AN];
  #pragma unroll
  for (int i2=0;i2<AM;++i2)
    #pragma unroll
    for (int j=0;j<AN;++j)
      acc[i2][j] = (f32x4){0.f,0.f,0.f,0.f};

  #pragma unroll
  for (int p=0;p<PA;++p) gload_lds16(ag[p], &As[aldst[p]]);
  #pragma unroll
  for (int p=0;p<PB;++p) gload_lds16(bg[p], &Bs[bldst[p]]);

  int nk = K / BK;
  for (int ki = 0; ki < nk; ++ki) {
    __syncthreads();
    int cur = ki & 1, nxt = cur ^ 1;
    if (ki + 1 < nk) {
      int kk = (ki + 1) * BK;
      #pragma unroll
      for (int p=0;p<PA;++p) gload_lds16(ag[p] + kk, &As[nxt*ASTG + aldst[p]]);
      #pragma unroll
      for (int p=0;p<PB;++p) gload_lds16(bg[p] + kk, &Bs[nxt*BSTG + bldst[p]]);
    }
    #pragma unroll
    for (int kh=0;kh<NKH;++kh) {
      short8 af[AM], bfr[AN];
      #pragma unroll
      for (int i2=0;i2<AM;++i2) af[i2] = *(const short8*)&As[cur*ASTG + aoff[kh][i2]];
      #pragma unroll
      for (int j=0;j<AN;++j) bfr[j] = *(const short8*)&Bs[cur*BSTG + boff[kh][j]];
      #pragma unroll
      for (int i2=0;i2<AM;++i2)
        #pragma unroll
        for (int j=0;j<AN;++j)
          acc[i2][j] = __builtin_amdgcn_mfma_f32_16x16x32_bf16(af[i2], bfr[j], acc[i2][j], 0, 0, 0);
    }
  }

  // weighted-partial setup (next layer's decay), row-in-chunk = quad*4+reg
  float wnext = 0.f, invw = 0.f, pwbase = 0.f;
  if (EPI == 1 && partW) {
    wnext = decay_w(kvec, wl);
    invw = 1.0f / wnext;
    pwbase = 1.0f;
    for (int q = 0; q < 15 - quad*4; ++q) pwbase *= wnext;  // w^(15-quad*4)
  }

  #pragma unroll
  for (int i2=0;i2<AM;++i2) {
    int rowb = m0 + wr*WM + i2*16 + quad*4;
    #pragma unroll
    for (int j=0;j<AN;++j) {
      int col = n0 + wc*WN + j*16 + r;
      float bv = 0.f;
      if (EPI != 2) bv = bias[col];
      float ps = 0.f, psW = 0.f, pw = pwbase;
      #pragma unroll
      for (int reg=0;reg<4;++reg) {
        size_t idx = (size_t)(rowb + reg) * N + col;
        float z = acc[i2][j][reg] + bv;
        if (EPI == 1) {
          float hv = C[idx] + z;
          C[idx] = hv;
          ps += hv;
          if (partW) { psW += pw * hv; pw *= invw; }
          if (Cb) Cb[idx] = f2bf(hv);
        } else {
          C[idx] = z;
        }
      }
      if (EPI == 1 && part) {
        ps += __shfl_xor(ps, 16);
        ps += __shfl_xor(ps, 32);
        if (partW) {
          psW += __shfl_xor(psW, 16);
          psW += __shfl_xor(psW, 32);
        }
        if (quad == 0) {
          int chunk = (m0 + wr*WM + i2*16) >> 4;   // TSF=16
          part[(size_t)chunk * N + col] = ps;
          if (partW) partW[(size_t)chunk * N + col] = psW;
        }
      }
    }
  }
}

extern "C" void kernel_launch(void* const* d_in, const int* in_sizes, int n_in,
                              void* d_out, int out_size, void* d_ws, size_t ws_size,
                              hipStream_t stream) {
  const int*   x     = (const int*)  d_in[0];
  const float* embed = (const float*)d_in[1];
  const float* kvec  = (const float*)d_in[2];
  const float* g     = (const float*)d_in[3];
  const float* bt    = (const float*)d_in[4];
  const float* W1    = (const float*)d_in[5];
  const float* b1    = (const float*)d_in[6];
  const float* W2    = (const float*)d_in[7];
  const float* b2    = (const float*)d_in[8];
  float* out = (float*)d_out;

  const size_t NTD = (size_t)Bc * Tc * Dc;   // 4,194,304
  const size_t NTH = (size_t)Bc * Tc * Hc;   // 16,777,216
  char* wsb = (char*)d_ws;
  float* h      = (float*)wsb;                wsb += NTD*4;               // 16MB
  float* tmpA   = (float*)wsb;                wsb += NTD*4;               // 16MB (th)
  float* partA  = (float*)wsb;                wsb += (size_t)Bc*NCF*Dc*4; // 1MB
  float* partB  = (float*)wsb;                wsb += (size_t)Bc*NCF*Dc*4; // 1MB
  float* partW  = (float*)wsb;                wsb += (size_t)Bc*NCF*Dc*4; // 1MB
  unsigned short* yb   = (unsigned short*)wsb; wsb += NTD*2;              // 8MB
  unsigned short* a1b  = (unsigned short*)wsb; wsb += NTH*2;              // 32MB
  unsigned short* hb   = (unsigned short*)wsb; wsb += NTD*2;              // 8MB
  unsigned short* W1t  = (unsigned short*)wsb; wsb += (size_t)3*Dc*Hc*2;  // 6MB
  unsigned short* W2t  = (unsigned short*)wsb; wsb += (size_t)3*Dc*Hc*2;  // 6MB
  unsigned short* emb  = (unsigned short*)wsb; wsb += (size_t)Vc*Dc*2;

  // merged weight prep (1 dispatch); emb branch: 128 blocks x 256thr x 4el
  wprep<<<dim3(6144 + (Vc*Dc)/1024), 256, 0, stream>>>(
      W1, W1t, W2, W2t, embed, emb);

  // prologue
  embed_part<<<dim3(NCF, Bc), 1024, 0, stream>>>(x, embed, tmpA, partA);
  part_prefix<<<dim3(256), 512, 0, stream>>>(partA);
  bd_apply<<<dim3(NCF, Bc), 512, 0, stream>>>(tmpA, partA, x, embed, h,
                                              partB, partW, kvec);
  part_prefix<<<dim3(256), 512, 0, stream>>>(partB);

  for (int l = 0; l < 3; ++l) {
    mag_scan_ln<<<dim3(NCF, Bc), 512, 0, stream>>>(h, partB, partW, kvec, l,
                                                   g, bt, yb);
    // z = gelu(y @ W1 + b1): M=8192 N=2048 K=512
    // dedicated 256x256 8-wave phase-split, ring-4 lead-3, 256 blocks
    mgemm1<<<dim3(256), 512, 0, stream>>>(
        yb, W1t + (size_t)l*Hc*Dc, b1 + (size_t)l*Hc, a1b, Hc, Dc, 32);
    // h += z @ W2 + b2 (+ raw & weighted chunk partials for layer l+1)
    // M=8192 N=512 K=2048; 128x64 BK=64 dbuf (best-measured config, 43us)
    mgemm<1,128,64,64><<<dim3(64*(Dc/64)), 256, 0, stream>>>(
        a1b, W2t + (size_t)l*Dc*Hc, b2 + (size_t)l*Dc, h,
        (l == 2) ? hb : nullptr,
        (l < 2) ? partB : nullptr, (l < 2) ? partW : nullptr, kvec, l + 1,
        Dc, Hc, 64);
    if (l < 2) part_prefix<<<dim3(256), 512, 0, stream>>>(partB);
  }
  // out = h @ embed^T: M=8192 N=256 K=512; 64x64 BK=32 dbuf, nrow=128
  mgemm<2,64,64,32><<<dim3(128*(Vc/64)), 256, 0, stream>>>(
      hb, emb, nullptr, out, nullptr, nullptr, nullptr, kvec, 0,
      Vc, Dc, 128);
}

// Round 13
// 390.664 us; speedup vs baseline: 1.0220x; 1.0056x over previous
//
#include <hip/hip_runtime.h>
#include <math.h>

// DeltaLM: B=4 T=2048 D=512 H=2048 L=3 V=256
// decay einsum == geometric scan S[i]=h[i]+w*S[i-1], w=exp(-softplus(k)).
// Round 29 (FINAL): champion locked. R10=390.8, R12=392.8 (reproduction,
// within noise). 13 variants over 12 rounds: GEMM2 pinned 43-50us across
// six schedule families with all-pipes-idle counters (structure-space
// floor, not a hardware roofline); GEMM1's 8-wave 256^2 phase-split was
// the one structural win (-25us); dedicated kernels per rule #19 (co-
// compile regression observed and fixed); rcpf + 3-term erf + vectorized
// wprep banked. Remaining micro-candidates rejected on arithmetic or
// correctness-risk grounds. This is the verified best configuration.

constexpr int Bc = 4, Tc = 2048, Dc = 512, Hc = 2048, Vc = 256;
constexpr int TSF = 16, NCF = 128;

typedef __attribute__((ext_vector_type(8))) short short8;
typedef __attribute__((ext_vector_type(4))) float f32x4;

__device__ inline unsigned short f2bf(float f) {  // RNE fp32->bf16
  unsigned int u = __float_as_uint(f);
  u += 0x7fffu + ((u >> 16) & 1u);
  return (unsigned short)(u >> 16);
}

__device__ inline void gload_lds16(const void* g, void* l) {
  __builtin_amdgcn_global_load_lds(
      (const __attribute__((address_space(1))) void*)g,
      (__attribute__((address_space(3))) void*)l, 16, 0, 0);
}

template<int N> __device__ inline void wvm() {
  if constexpr (N == 0)      asm volatile("s_waitcnt vmcnt(0)" ::: "memory");
  else if constexpr (N == 4) asm volatile("s_waitcnt vmcnt(4)" ::: "memory");
  else if constexpr (N == 8) asm volatile("s_waitcnt vmcnt(8)" ::: "memory");
  else static_assert(N == 0, "unsupported vmcnt");
}
__device__ inline void barrier_raw() {
  asm volatile("s_barrier" ::: "memory");
}

// gelu(z) = 0.5 z (1+erf(z/sqrt2)); erf via A&S 7.1.25, |eps|<=2.5e-5
// (bf16 rel eps ~2e-3 -> approximation error invisible after f2bf)
__device__ inline float gelu_f(float z) {
  float x = z * 0.707106781186547524f;
  float ax = fabsf(x);
  float t = __builtin_amdgcn_rcpf(fmaf(0.47047f, ax, 1.0f));
  float poly = t*(0.3480242f + t*(-0.0958798f + t*0.7478556f));
  float er = 1.0f - poly * __expf(-ax*ax);
  er = copysignf(er, x);
  return 0.5f * z * (1.0f + er);
}

__device__ inline float decay_w(const float* kvec, int l) {
  float kk = kvec[l];
  float sp = kk > 0.f ? kk + log1pf(expf(-kk)) : log1pf(expf(kk));
  return expf(-sp);
}

// ---------- merged weight prep: W1t, W2t (transpose->bf16) + emb ----------
__device__ inline void tr32(const float* Wl, unsigned short* Wtl,
                            int R, int C, int c0, int r0, int tid,
                            float (*tile)[33]) {
  int tx = tid & 31, ty = tid >> 5;
  for (int i = ty; i < 32; i += 8)
    tile[i][tx] = Wl[(size_t)(r0+i)*C + (c0+tx)];
  __syncthreads();
  int rx = tid & 7, ry = tid >> 3;   // ry: c-row 0..31, rx*4: r offset
  ushort4 o;
  o.x = f2bf(tile[rx*4+0][ry]);
  o.y = f2bf(tile[rx*4+1][ry]);
  o.z = f2bf(tile[rx*4+2][ry]);
  o.w = f2bf(tile[rx*4+3][ry]);
  *(ushort4*)&Wtl[(size_t)(c0+ry)*R + (r0 + rx*4)] = o;
}

__global__ __launch_bounds__(256) void wprep(
    const float* __restrict__ W1, unsigned short* __restrict__ W1t,
    const float* __restrict__ W2, unsigned short* __restrict__ W2t,
    const float* __restrict__ embed, unsigned short* __restrict__ emb)
{
  __shared__ float tile[32][33];
  int bid = blockIdx.x, tid = threadIdx.x;
  if (bid < 3072) {            // W1: (L, Dc, Hc) -> (L, Hc, Dc) bf16
    int l = bid >> 10, rem = bid & 1023;
    int cx = rem & 63, ry = rem >> 6;      // C/32=64, R/32=16
    tr32(W1 + (size_t)l*Dc*Hc, W1t + (size_t)l*Dc*Hc, Dc, Hc,
         cx*32, ry*32, tid, tile);
  } else if (bid < 6144) {     // W2: (L, Hc, Dc) -> (L, Dc, Hc) bf16
    int b2 = bid - 3072;
    int l = b2 >> 10, rem = b2 & 1023;
    int cx = rem & 15, ry = rem >> 4;      // C/32=16, R/32=64
    tr32(W2 + (size_t)l*Hc*Dc, W2t + (size_t)l*Hc*Dc, Hc, Dc,
         cx*32, ry*32, tid, tile);
  } else {                     // emb: fp32 -> bf16, 4 elems/thread
    int i = ((bid - 6144)*256 + tid) * 4;
    if (i < Vc*Dc) {
      float4 v = *(const float4*)&embed[i];
      ushort4 o;
      o.x = f2bf(v.x); o.y = f2bf(v.y); o.z = f2bf(v.z); o.w = f2bf(v.w);
      *(ushort4*)&emb[i] = o;
    }
  }
}

// ---------- embed gather + cumprod + tanh + chunk sums (fused) ----------
__global__ __launch_bounds__(1024) void embed_part(
    const int* __restrict__ x, const float* __restrict__ embed,
    float* __restrict__ th, float* __restrict__ partA)
{
  int c = blockIdx.x, b = blockIdx.y;
  int wv = threadIdx.x >> 6, lane = threadIdx.x & 63;
  int token = b*Tc + c*TSF + wv;
  int row = x[token];
  const float* e = embed + (size_t)row * Dc + lane * 8;
  float v[8];
  {
    float4 a = *(const float4*)e;
    float4 bb = *(const float4*)(e + 4);
    v[0]=a.x; v[1]=a.y; v[2]=a.z; v[3]=a.w;
    v[4]=bb.x; v[5]=bb.y; v[6]=bb.z; v[7]=bb.w;
  }
  float p = v[0];
  #pragma unroll
  for (int j=1;j<8;++j) p *= v[j];
  float incl = p;
  #pragma unroll
  for (int off=1; off<64; off<<=1) {
    float t = __shfl_up(incl, off);
    if (lane >= off) incl *= t;
  }
  float excl = __shfl_up(incl, 1);
  if (lane == 0) excl = 1.0f;
  float cc = excl;
  float o[8];
  #pragma unroll
  for (int j=0;j<8;++j) { cc *= v[j]; o[j] = tanhf(cc); }
  float* dst = th + (size_t)token * Dc + lane * 8;
  *(float4*)dst     = make_float4(o[0],o[1],o[2],o[3]);
  *(float4*)(dst+4) = make_float4(o[4],o[5],o[6],o[7]);
  __syncthreads();
  int d = threadIdx.x;
  if (d < Dc) {
    const float* pp = th + ((size_t)b*Tc + c*TSF)*Dc + d;
    float s = 0.f;
    #pragma unroll
    for (int t=0;t<TSF;++t) s += pp[(size_t)t*Dc];
    partA[((size_t)b*NCF + c)*Dc + d] = s;
  }
}

// ---------- in-place exclusive prefix over 128 chunks: 1 wave per (b,d) ---
__global__ __launch_bounds__(512) void part_prefix(float* __restrict__ part)
{
  int pair = blockIdx.x * 8 + (threadIdx.x >> 6);   // 2048 (b,d) pairs
  int lane = threadIdx.x & 63;
  int b = pair >> 9, d = pair & 511;
  size_t i0 = ((size_t)b*NCF + 2*lane)*Dc + d;
  float v0 = part[i0];
  float v1 = part[i0 + Dc];
  float ps = v0 + v1;
  float incl = ps;
  #pragma unroll
  for (int off=1; off<64; off<<=1) {
    float t = __shfl_up(incl, off);
    if (lane >= off) incl += t;
  }
  float excl = incl - ps;
  part[i0]      = excl;
  part[i0 + Dc] = excl + v0;
}

// ---------- bd = cumsum_t(th); h = embed[x]*(1+bd); chunk sums + weighted -
__global__ __launch_bounds__(512) void bd_apply(
    const float* __restrict__ th, const float* __restrict__ partA,
    const int* __restrict__ x, const float* __restrict__ embed,
    float* __restrict__ h, float* __restrict__ partB,
    float* __restrict__ partW, const float* __restrict__ kvec)
{
  int c = blockIdx.x, b = blockIdx.y, d = threadIdx.x;
  float w0 = decay_w(kvec, 0);
  float acc = partA[((size_t)b*NCF + c)*Dc + d];   // exclusive prefix (th)
  float hsum = 0.f, psW = 0.f;
  #pragma unroll
  for (int t=0;t<TSF;++t) {
    int tt = c*TSF + t;
    size_t idx = ((size_t)b*Tc + tt)*Dc + d;
    acc += th[idx];
    int row = x[b*Tc + tt];
    float e = embed[(size_t)row*Dc + d];
    float hv = e * (1.0f + acc);
    h[idx] = hv;
    hsum += hv;
    psW = psW * w0 + hv;                           // Horner: sum w^(15-t) hv
  }
  partB[((size_t)b*NCF + c)*Dc + d] = hsum;        // raw chunk sum (h)
  partW[((size_t)b*NCF + c)*Dc + d] = psW;         // weighted (layer-0 w)
}

// ---------- fused: mag (LDS only) + geometric scan + LayerNorm -> bf16 ----
__global__ __launch_bounds__(512) void mag_scan_ln(
    const float* __restrict__ h, const float* __restrict__ part,
    const float* __restrict__ partW,
    const float* __restrict__ kvec, int l,
    const float* __restrict__ g, const float* __restrict__ bt,
    unsigned short* __restrict__ yb)
{
  __shared__ float redA[8][TSF];
  __shared__ float redB[8][TSF];
  __shared__ float mag[TSF], muS[TSF], rsS[TSF];
  int c = blockIdx.x, b = blockIdx.y, d = threadIdx.x;
  int lane = d & 63, wv = d >> 6;
  float acc = part[((size_t)b*NCF + c)*Dc + d];    // exclusive prefix (h)
  int t0 = c * TSF;
  const float* hbase = h + (size_t)b*Tc*Dc + d;
  float hp = (t0 > 0) ? hbase[(size_t)(t0-1)*Dc] : 0.f;
  float hv[TSF];
  #pragma unroll
  for (int t=0;t<TSF;++t) {
    hv[t] = hbase[(size_t)(t0+t)*Dc];
    acc += hv[t];
    float diff = acc - hp;
    hp = hv[t];
    float s = diff * diff;
    #pragma unroll
    for (int off=32; off; off>>=1) s += __shfl_down(s, off);
    if (!lane) redA[wv][t] = s;
  }
  float w = decay_w(kvec, l);
  float s = (c > 0) ? partW[((size_t)b*NCF + (c-1))*Dc + d] : 0.f;
  __syncthreads();
  if (d < TSF) {
    float m = 0.f;
    #pragma unroll
    for (int w2=0;w2<8;++w2) m += redA[w2][d];
    mag[d] = sqrtf(m);
  }
  __syncthreads();
  #pragma unroll
  for (int t=0;t<TSF;++t) {
    s = hv[t] + w * s;
    float cv = mag[t] * fabsf(s);
    hv[t] = cv;
    float s1 = cv, s2 = cv * cv;
    #pragma unroll
    for (int off=32; off; off>>=1) {
      s1 += __shfl_down(s1, off);
      s2 += __shfl_down(s2, off);
    }
    if (!lane) { redA[wv][t] = s1; redB[wv][t] = s2; }
  }
  __syncthreads();
  if (d < TSF) {
    float m1 = 0.f, m2 = 0.f;
    #pragma unroll
    for (int w2=0;w2<8;++w2) { m1 += redA[w2][d]; m2 += redB[w2][d]; }
    float mu = m1 * (1.f/Dc);
    float var = fmaxf(m2 * (1.f/Dc) - mu*mu, 0.f);
    muS[d] = mu;
    rsS[d] = rsqrtf(var + 1e-3f);
  }
  __syncthreads();
  float gv = g[l*Dc + d], bv = bt[l*Dc + d];
  unsigned short* yp = yb + ((size_t)b*Tc + t0)*Dc + d;
  #pragma unroll
  for (int t=0;t<TSF;++t)
    yp[(size_t)t*Dc] = f2bf((hv[t] - muS[t]) * rsS[t] * gv + bv);
}

// CH=4: (row>>1)&3 ; CH=8: row&7.
template<int CH> __device__ inline int swz(int row) {
  if constexpr (CH == 8) return row & 7;
  else return (row >> 1) & 3;
}

// ---------- GEMM1: dedicated 256x256 8-wave phase-split, ring-4 BK=32 ----
// R25-verified. Cb = bf16(gelu(A@Bt^T + bias)).
__global__ __launch_bounds__(512, 2) void mgemm1(
    const unsigned short* __restrict__ A,
    const unsigned short* __restrict__ Bt,
    const float* __restrict__ bias,
    unsigned short* __restrict__ Cb,
    int N, int K, int nrow)
{
  constexpr int TM = 256, TN = 256, BK = 32;
  constexpr int PA = 2, PB = 2;
  constexpr int ASTG = TM*BK, BSTG = TN*BK;
  __shared__ unsigned short As[4*ASTG];      // 4 x 16KB
  __shared__ unsigned short Bs[4*BSTG];      // 4 x 16KB
  int tid = threadIdx.x;
  int lane = tid & 63, w = tid >> 6;
  int wr = w >> 2, wc = w & 3;               // 2(M) x 4(N) wave grid
  int bid = blockIdx.x;
  int xcd = bid & 7, i = bid >> 3;
  int npx = nrow >> 3;
  int m0 = (xcd * npx + (i % npx)) * TM;
  int n0 = (i / npx) * TN;

  const unsigned short* ag[PA];
  const unsigned short* bg[PB];
  int aldst[PA], bldst[PB];
  #pragma unroll
  for (int p=0;p<PA;++p) {
    int ci = p*512 + tid;
    int row = ci >> 2, cp = ci & 3;
    int cg = cp ^ ((row >> 1) & 3);
    ag[p] = A + (size_t)(m0+row)*K + cg*8;
    aldst[p] = (p*512 + w*64)*8;
  }
  #pragma unroll
  for (int p=0;p<PB;++p) {
    int ci = p*512 + tid;
    int row = ci >> 2, cp = ci & 3;
    int cg = cp ^ ((row >> 1) & 3);
    bg[p] = Bt + (size_t)(n0+row)*K + cg*8;
    bldst[p] = (p*512 + w*64)*8;
  }

  int r = lane & 15, quad = lane >> 4;
  int sz = (quad ^ ((r >> 1) & 3)) * 8;      // swizzled chunk offset (shorts)
  int aoff[8], boff[4];
  #pragma unroll
  for (int fi=0; fi<8; ++fi)
    aoff[fi] = (wr*128 + fi*16 + r)*BK + sz;
  #pragma unroll
  for (int fj=0; fj<4; ++fj)
    boff[fj] = (wc*64 + fj*16 + r)*BK + sz;

  f32x4 acc[8][4];
  #pragma unroll
  for (int fi=0;fi<8;++fi)
    #pragma unroll
    for (int fj=0;fj<4;++fj)
      acc[fi][fj] = (f32x4){0.f,0.f,0.f,0.f};

  auto STAGE_A = [&](int t) {
    int kk = t * BK, sl = t & 3;
    #pragma unroll
    for (int p=0;p<PA;++p) gload_lds16(ag[p] + kk, &As[sl*ASTG + aldst[p]]);
  };
  auto STAGE_B = [&](int t) {
    int kk = t * BK, sl = t & 3;
    #pragma unroll
    for (int p=0;p<PB;++p) gload_lds16(bg[p] + kk, &Bs[sl*BSTG + bldst[p]]);
  };

  int nk = K / BK;                 // 16 for GEMM1
  STAGE_A(0); STAGE_B(0);
  STAGE_A(1); STAGE_B(1);
  STAGE_A(2); STAGE_B(2);

  for (int kt = 0; kt < nk; ++kt) {
    if (kt < nk-2)       wvm<8>();
    else if (kt == nk-2) wvm<4>();
    else                 wvm<0>();
    barrier_raw();
    int s = kt & 3;
    short8 bfr[4], af[4];
    #pragma unroll
    for (int fj=0;fj<4;++fj) bfr[fj] = *(const short8*)&Bs[s*BSTG + boff[fj]];
    #pragma unroll
    for (int fi=0;fi<4;++fi) af[fi] = *(const short8*)&As[s*ASTG + aoff[fi]];
    if (kt + 3 < nk) STAGE_A(kt + 3);
    __builtin_amdgcn_s_setprio(1);
    #pragma unroll
    for (int fi=0;fi<4;++fi)
      #pragma unroll
      for (int fj=0;fj<4;++fj)
        acc[fi][fj] = __builtin_amdgcn_mfma_f32_16x16x32_bf16(
            af[fi], bfr[fj], acc[fi][fj], 0, 0, 0);
    __builtin_amdgcn_s_setprio(0);
    barrier_raw();
    #pragma unroll
    for (int fi=0;fi<4;++fi) af[fi] = *(const short8*)&As[s*ASTG + aoff[4+fi]];
    if (kt + 3 < nk) STAGE_B(kt + 3);
    __builtin_amdgcn_s_setprio(1);
    #pragma unroll
    for (int fi=0;fi<4;++fi)
      #pragma unroll
      for (int fj=0;fj<4;++fj)
        acc[4+fi][fj] = __builtin_amdgcn_mfma_f32_16x16x32_bf16(
            af[fi], bfr[fj], acc[4+fi][fj], 0, 0, 0);
    __builtin_amdgcn_s_setprio(0);
  }

  #pragma unroll
  for (int fi=0;fi<8;++fi) {
    int rowb = m0 + wr*128 + fi*16 + quad*4;
    #pragma unroll
    for (int fj=0;fj<4;++fj) {
      int col = n0 + wc*64 + fj*16 + r;
      float bv = bias[col];
      #pragma unroll
      for (int reg=0;reg<4;++reg) {
        size_t idx = (size_t)(rowb + reg) * N + col;
        Cb[idx] = f2bf(gelu_f(acc[fi][fj][reg] + bv));
      }
    }
  }
}

// ---------- bf16 MFMA GEMM, dbuf LDS, 1 barrier/K-step, XCD supertiles ----
// EPI 1: C+=z+bias (+ raw and weighted chunk partials via butterfly,
// opt Cb mirror); EPI 2: C=z.
template<int EPI, int TM, int TN, int BK>
__global__ __launch_bounds__(256) void mgemm(
    const unsigned short* __restrict__ A,
    const unsigned short* __restrict__ Bt,
    const float* __restrict__ bias,
    float* __restrict__ C, unsigned short* __restrict__ Cb,
    float* __restrict__ part, float* __restrict__ partW,
    const float* __restrict__ kvec, int wl,
    int N, int K, int nrow)
{
  constexpr int CH = BK / 8;
  constexpr int PA = TM*CH/256, PB = TN*CH/256;
  constexpr int WM = TM/2, WN = TN/2;
  constexpr int AM = WM/16, AN = WN/16;
  constexpr int NKH = BK/32;
  constexpr int ASTG = TM*BK, BSTG = TN*BK;
  __shared__ unsigned short As[2*ASTG];
  __shared__ unsigned short Bs[2*BSTG];
  int tid = threadIdx.x;
  int lane = tid & 63, w = tid >> 6;
  int wr = w >> 1, wc = w & 1;
  int bid = blockIdx.x;
  int xcd = bid & 7, i = bid >> 3;
  int npx = nrow >> 3;
  int m0 = (xcd * npx + (i % npx)) * TM;
  int n0 = (i / npx) * TN;

  const unsigned short* ag[PA];
  const unsigned short* bg[PB];
  int aldst[PA], bldst[PB];
  #pragma unroll
  for (int p=0;p<PA;++p) {
    int ci = p*256 + tid;
    int row = ci / CH, cp = ci % CH;
    int cg = cp ^ swz<CH>(row);
    ag[p] = A + (size_t)(m0+row)*K + cg*8;
    aldst[p] = (p*256 + w*64)*8;
  }
  #pragma unroll
  for (int p=0;p<PB;++p) {
    int ci = p*256 + tid;
    int row = ci / CH, cp = ci % CH;
    int cg = cp ^ swz<CH>(row);
    bg[p] = Bt + (size_t)(n0+row)*K + cg*8;
    bldst[p] = (p*256 + w*64)*8;
  }

  int r = lane & 15, quad = lane >> 4;
  int aoff[NKH][AM], boff[NKH][AN];
  #pragma unroll
  for (int kh=0;kh<NKH;++kh) {
    int cb = kh*4 + quad;
    #pragma unroll
    for (int i2=0;i2<AM;++i2)
      aoff[kh][i2] = (wr*WM + i2*16 + r)*BK + ((cb ^ swz<CH>(r)) & (CH-1))*8;
    #pragma unroll
    for (int j=0;j<AN;++j)
      boff[kh][j] = (wc*WN + j*16 + r)*BK + ((cb ^ swz<CH>(r)) & (CH-1))*8;
  }

  f32x4 acc[AM][AN];
  #pragma unroll
  for (int i2=0;i2<AM;++i2)
    #pragma unroll
    for (int j=0;j<AN;++j)
      acc[i2][j] = (f32x4){0.f,0.f,0.f,0.f};

  #pragma unroll
  for (int p=0;p<PA;++p) gload_lds16(ag[p], &As[aldst[p]]);
  #pragma unroll
  for (int p=0;p<PB;++p) gload_lds16(bg[p], &Bs[bldst[p]]);

  int nk = K / BK;
  for (int ki = 0; ki < nk; ++ki) {
    __syncthreads();
    int cur = ki & 1, nxt = cur ^ 1;
    if (ki + 1 < nk) {
      int kk = (ki + 1) * BK;
      #pragma unroll
      for (int p=0;p<PA;++p) gload_lds16(ag[p] + kk, &As[nxt*ASTG + aldst[p]]);
      #pragma unroll
      for (int p=0;p<PB;++p) gload_lds16(bg[p] + kk, &Bs[nxt*BSTG + bldst[p]]);
    }
    #pragma unroll
    for (int kh=0;kh<NKH;++kh) {
      short8 af[AM], bfr[AN];
      #pragma unroll
      for (int i2=0;i2<AM;++i2) af[i2] = *(const short8*)&As[cur*ASTG + aoff[kh][i2]];
      #pragma unroll
      for (int j=0;j<AN;++j) bfr[j] = *(const short8*)&Bs[cur*BSTG + boff[kh][j]];
      #pragma unroll
      for (int i2=0;i2<AM;++i2)
        #pragma unroll
        for (int j=0;j<AN;++j)
          acc[i2][j] = __builtin_amdgcn_mfma_f32_16x16x32_bf16(af[i2], bfr[j], acc[i2][j], 0, 0, 0);
    }
  }

  // weighted-partial setup (next layer's decay), row-in-chunk = quad*4+reg
  float wnext = 0.f, invw = 0.f, pwbase = 0.f;
  if (EPI == 1 && partW) {
    wnext = decay_w(kvec, wl);
    invw = 1.0f / wnext;
    pwbase = 1.0f;
    for (int q = 0; q < 15 - quad*4; ++q) pwbase *= wnext;  // w^(15-quad*4)
  }

  #pragma unroll
  for (int i2=0;i2<AM;++i2) {
    int rowb = m0 + wr*WM + i2*16 + quad*4;
    #pragma unroll
    for (int j=0;j<AN;++j) {
      int col = n0 + wc*WN + j*16 + r;
      float bv = 0.f;
      if (EPI != 2) bv = bias[col];
      float ps = 0.f, psW = 0.f, pw = pwbase;
      #pragma unroll
      for (int reg=0;reg<4;++reg) {
        size_t idx = (size_t)(rowb + reg) * N + col;
        float z = acc[i2][j][reg] + bv;
        if (EPI == 1) {
          float hv = C[idx] + z;
          C[idx] = hv;
          ps += hv;
          if (partW) { psW += pw * hv; pw *= invw; }
          if (Cb) Cb[idx] = f2bf(hv);
        } else {
          C[idx] = z;
        }
      }
      if (EPI == 1 && part) {
        ps += __shfl_xor(ps, 16);
        ps += __shfl_xor(ps, 32);
        if (partW) {
          psW += __shfl_xor(psW, 16);
          psW += __shfl_xor(psW, 32);
        }
        if (quad == 0) {
          int chunk = (m0 + wr*WM + i2*16) >> 4;   // TSF=16
          part[(size_t)chunk * N + col] = ps;
          if (partW) partW[(size_t)chunk * N + col] = psW;
        }
      }
    }
  }
}

extern "C" void kernel_launch(void* const* d_in, const int* in_sizes, int n_in,
                              void* d_out, int out_size, void* d_ws, size_t ws_size,
                              hipStream_t stream) {
  const int*   x     = (const int*)  d_in[0];
  const float* embed = (const float*)d_in[1];
  const float* kvec  = (const float*)d_in[2];
  const float* g     = (const float*)d_in[3];
  const float* bt    = (const float*)d_in[4];
  const float* W1    = (const float*)d_in[5];
  const float* b1    = (const float*)d_in[6];
  const float* W2    = (const float*)d_in[7];
  const float* b2    = (const float*)d_in[8];
  float* out = (float*)d_out;

  const size_t NTD = (size_t)Bc * Tc * Dc;   // 4,194,304
  const size_t NTH = (size_t)Bc * Tc * Hc;   // 16,777,216
  char* wsb = (char*)d_ws;
  float* h      = (float*)wsb;                wsb += NTD*4;               // 16MB
  float* tmpA   = (float*)wsb;                wsb += NTD*4;               // 16MB (th)
  float* partA  = (float*)wsb;                wsb += (size_t)Bc*NCF*Dc*4; // 1MB
  float* partB  = (float*)wsb;                wsb += (size_t)Bc*NCF*Dc*4; // 1MB
  float* partW  = (float*)wsb;                wsb += (size_t)Bc*NCF*Dc*4; // 1MB
  unsigned short* yb   = (unsigned short*)wsb; wsb += NTD*2;              // 8MB
  unsigned short* a1b  = (unsigned short*)wsb; wsb += NTH*2;              // 32MB
  unsigned short* hb   = (unsigned short*)wsb; wsb += NTD*2;              // 8MB
  unsigned short* W1t  = (unsigned short*)wsb; wsb += (size_t)3*Dc*Hc*2;  // 6MB
  unsigned short* W2t  = (unsigned short*)wsb; wsb += (size_t)3*Dc*Hc*2;  // 6MB
  unsigned short* emb  = (unsigned short*)wsb; wsb += (size_t)Vc*Dc*2;

  // merged weight prep (1 dispatch); emb branch: 128 blocks x 256thr x 4el
  wprep<<<dim3(6144 + (Vc*Dc)/1024), 256, 0, stream>>>(
      W1, W1t, W2, W2t, embed, emb);

  // prologue
  embed_part<<<dim3(NCF, Bc), 1024, 0, stream>>>(x, embed, tmpA, partA);
  part_prefix<<<dim3(256), 512, 0, stream>>>(partA);
  bd_apply<<<dim3(NCF, Bc), 512, 0, stream>>>(tmpA, partA, x, embed, h,
                                              partB, partW, kvec);
  part_prefix<<<dim3(256), 512, 0, stream>>>(partB);

  for (int l = 0; l < 3; ++l) {
    mag_scan_ln<<<dim3(NCF, Bc), 512, 0, stream>>>(h, partB, partW, kvec, l,
                                                   g, bt, yb);
    // z = gelu(y @ W1 + b1): M=8192 N=2048 K=512
    // dedicated 256x256 8-wave phase-split, ring-4 lead-3, 256 blocks
    mgemm1<<<dim3(256), 512, 0, stream>>>(
        yb, W1t + (size_t)l*Hc*Dc, b1 + (size_t)l*Hc, a1b, Hc, Dc, 32);
    // h += z @ W2 + b2 (+ raw & weighted chunk partials for layer l+1)
    // M=8192 N=512 K=2048; 128x64 BK=64 dbuf (best-measured config, 43us)
    mgemm<1,128,64,64><<<dim3(64*(Dc/64)), 256, 0, stream>>>(
        a1b, W2t + (size_t)l*Dc*Hc, b2 + (size_t)l*Dc, h,
        (l == 2) ? hb : nullptr,
        (l < 2) ? partB : nullptr, (l < 2) ? partW : nullptr, kvec, l + 1,
        Dc, Hc, 64);
    if (l < 2) part_prefix<<<dim3(256), 512, 0, stream>>>(partB);
  }
  // out = h @ embed^T: M=8192 N=256 K=512; 64x64 BK=32 dbuf, nrow=128
  mgemm<2,64,64,32><<<dim3(128*(Vc/64)), 256, 0, stream>>>(
      hb, emb, nullptr, out, nullptr, nullptr, nullptr, kvec, 0,
      Vc, Dc, 128);
}